// Round 11
// baseline (389.105 us; speedup 1.0000x reference)
//
#include <hip/hip_runtime.h>

// ConvMGSA on MI355X. Inputs/outputs FLOAT32; intermediates bf16.
// N=4 G=8 CIN=COUT=256 K=3 M=4 D=64 H=W=32 HW=1024.
//
// R19: R18 + amdgpu_waves_per_eu(4,5) on attn. R18 post-mortem: allocator
//      derives its occupancy TARGET from LDS (20.5KB -> 8 waves/SIMD ->
//      VGPR cap 64 = 512/8) and spills the ~90 live regs (qv[8]+acc+scores)
//      -> 130MB scratch traffic. launch_bounds' 2nd arg only sets the floor.
//      waves_per_eu(4,5) caps the TARGET at 5 waves/SIMD -> budget ~102 ->
//      no spill, 5 blocks/CU (20 waves, +25% TLP vs R16's 16).
// Buffers: d_out[0:16.8M]=q->av, d_out[+16.8M]=relT; ws[0:16M]=k->hidden;
//          ws[16M:32M]=v->t1.

typedef unsigned short u16;
typedef unsigned int u32;
typedef __attribute__((ext_vector_type(8))) short bf16x8;
typedef __attribute__((ext_vector_type(4))) float f32x4;

__device__ __forceinline__ u32 fbits(float f) { u32 x; __builtin_memcpy(&x, &f, 4); return x; }
__device__ __forceinline__ float bf2f(u32 v) {
    u32 x = v << 16; float f; __builtin_memcpy(&f, &x, 4); return f;
}
__device__ __forceinline__ u16 f2bf(float f) {
    u32 x = fbits(f);
    u32 r = x + 0x7fffu + ((x >> 16) & 1u);
    return (u16)(r >> 16);
}
__device__ __forceinline__ u32 pack2bf(float a, float b) {
    return __builtin_amdgcn_perm(fbits(b) + 0x8000u, fbits(a) + 0x8000u, 0x07060302u);
}

__device__ __forceinline__ void unpack8(uint4 u, float* o) {
    o[0] = bf2f(u.x & 0xffff); o[1] = bf2f(u.x >> 16);
    o[2] = bf2f(u.y & 0xffff); o[3] = bf2f(u.y >> 16);
    o[4] = bf2f(u.z & 0xffff); o[5] = bf2f(u.z >> 16);
    o[6] = bf2f(u.w & 0xffff); o[7] = bf2f(u.w >> 16);
}
__device__ __forceinline__ void ld8bf(const u16* p, float* o) { unpack8(*(const uint4*)p, o); }
__device__ __forceinline__ void ld8f(const float* p, float* o) {
    float4 a = *(const float4*)p, b = *(const float4*)(p + 4);
    o[0] = a.x; o[1] = a.y; o[2] = a.z; o[3] = a.w;
    o[4] = b.x; o[5] = b.y; o[6] = b.z; o[7] = b.w;
}
__device__ __forceinline__ void st4bf(u16* p, const float* v) {
    ushort4 s; s.x = f2bf(v[0]); s.y = f2bf(v[1]); s.z = f2bf(v[2]); s.w = f2bf(v[3]);
    *(ushort4*)p = s;
}

#if defined(__has_builtin)
#if __has_builtin(__builtin_amdgcn_fdot2_f32_bf16)
#define HAVE_BFDOT 1
#endif
#endif
#ifdef HAVE_BFDOT
typedef __attribute__((ext_vector_type(2))) __bf16 v2bf;
__device__ __forceinline__ float dot2bf(u32 a, u32 b, float c) {
    return __builtin_amdgcn_fdot2_f32_bf16(__builtin_bit_cast(v2bf, a),
                                           __builtin_bit_cast(v2bf, b), c, false);
}
#else
__device__ __forceinline__ float dot2bf(u32 a, u32 b, float c) {
    return c + bf2f(a & 0xffff) * bf2f(b & 0xffff) + bf2f(a >> 16) * bf2f(b >> 16);
}
#endif
__device__ __forceinline__ float dot8bf(uint4 a, uint4 b, float c) {
    c = dot2bf(a.x, b.x, c); c = dot2bf(a.y, b.y, c);
    c = dot2bf(a.z, b.z, c); c = dot2bf(a.w, b.w, c);
    return c;
}

typedef const __attribute__((address_space(1))) u32 glob_u32;
typedef __attribute__((address_space(3))) u32 lds_u32;

// async global->LDS, 16B/lane, dest = wave-uniform base + lane*16
__device__ __forceinline__ void gl16(const void* g, void* l) {
    __builtin_amdgcn_global_load_lds((glob_u32*)g, (lds_u32*)l, 16, 0, 0);
}

// ---------------- rel transpose micro-kernel: relT[idx][m][e][d] bf16, 12KB ----------------
__global__ __launch_bounds__(256) void rel_kernel(const float* __restrict__ hm,
                                                  const float* __restrict__ wm,
                                                  u16* __restrict__ relT) {
    const int t = threadIdx.x;
    const int c0 = t << 3;                       // 8 contiguous channels (same e,m)
    const float* rb = (t < 128) ? (hm + (size_t)c0 * 3)
                                : (wm + (size_t)(c0 - 1024) * 3);
    float r[24];
    #pragma unroll
    for (int q = 0; q < 6; q++) {
        float4 f = *(const float4*)(rb + q * 4);
        r[q * 4] = f.x; r[q * 4 + 1] = f.y; r[q * 4 + 2] = f.z; r[q * 4 + 3] = f.w;
    }
    // m-major remap: c = e*256 + m*64 + d  ->  off = m*512 + e*64 + d
    const int obase = ((c0 >> 6) & 3) * 512 + (c0 >> 8) * 64 + (c0 & 63);
    #pragma unroll
    for (int idx = 0; idx < 3; idx++) {
        u32 pk[4];
        #pragma unroll
        for (int j = 0; j < 4; j++)
            pk[j] = pack2bf(r[(2 * j) * 3 + idx], r[(2 * j + 1) * 3 + idx]);
        *(uint4*)(relT + idx * 2048 + obase) = *(uint4*)pk;
    }
}

// ================= MFMA GEMM: C[o][p] = sum_i W[g][o][i] * B[i][p] =================
// BMODE: 1=bf16 i-major, 2=bf16 pixel-major M-MAJOR channels, 3=f32 i-major
// OM: 0=bf16 pixel-major M-MAJOR out (qkv); 1=bf16 channel-major +bias(+relu);
//     2=fused LN, bf16 scramble-flat out; 3=fused LN, f32 scramble-flat out.
// RF32: residual dtype for OM>=2 (1=f32, 0=bf16), channel-major [ng][256][1024].
template<int BMODE, int OM, int RELU, int RF32>
__global__ __launch_bounds__(256) void gemm_kernel(
    const float* __restrict__ A0, const float* __restrict__ A1,
    const float* __restrict__ A2, const void* __restrict__ B,
    const float* __restrict__ bias, const void* __restrict__ resid,
    const float* __restrict__ gamma, const float* __restrict__ beta,
    u16* __restrict__ O0, u16* __restrict__ O1, u16* __restrict__ O2) {
    __shared__ __align__(16) char smem[OM >= 2 ? 37376 : (OM == 1 ? 33792 : 20480)];
    u16* Al = (u16*)smem;              // [128][40] bf16  (o, k)
    u16* Bl = (u16*)(smem + 10240);    // [128][40] bf16  (p, k)
    float* Cl = (float*)smem;          // [64][132] f32   (epilogue transpose)
    float* red  = (float*)(smem + 33792);   // [2][2][128]
    float* mu_s = (float*)(smem + 35840);
    float* rs_s = (float*)(smem + 36352);
    float* g_s  = (float*)(smem + 36864);
    float* b_s  = (float*)(smem + 37120);

    const int tid = threadIdx.x;
    const int pt = blockIdx.x, ot = blockIdx.y;
    const int ngz = blockIdx.z, sel = ngz >> 5, ng = ngz & 31;
    const float* A = (sel == 0) ? A0 : (sel == 1) ? A1 : A2;
    u16* out      = (sel == 0) ? O0 : (sel == 1) ? O1 : O2;
    const int n = ng >> 3, g = ng & 7;
    const int p0 = pt << 7, o0 = ot << 7;
    const float* Ag = A + (size_t)g * 65536;

    if (OM >= 2 && tid < 64) { g_s[tid] = gamma[tid]; b_s[tid] = beta[tid]; }

    const int l = tid & 63, w = tid >> 6;
    const int mq = w >> 1;
    const int mw = mq << 6, nw = (w & 1) << 6;
    const int lrow = l & 15, lk = (l >> 4) << 3;

    f32x4 acc[4][4];
    #pragma unroll
    for (int i = 0; i < 4; i++)
        #pragma unroll
        for (int j = 0; j < 4; j++) acc[i][j] = (f32x4){0.f, 0.f, 0.f, 0.f};

    for (int k0 = 0; k0 < 256; k0 += 32) {
        {   // stage A: f32 weights, rows k-contiguous, pack2bf
            const int r = tid >> 1, cb = (tid & 1) << 4;
            const float* src = Ag + (size_t)(o0 + r) * 256 + k0 + cb;
            u32* dst = (u32*)&Al[r * 40 + cb];
            #pragma unroll
            for (int q = 0; q < 4; q++) {
                float4 f = *(const float4*)(src + q * 4);
                dst[q * 2]     = pack2bf(f.x, f.y);
                dst[q * 2 + 1] = pack2bf(f.z, f.w);
            }
        }
        if (BMODE == 2) {
            // pixel-major, m-major channels: k -> c = (k>>6)*512 + g*64 + (k&63)
            const int r = tid >> 1, cb = (tid & 1) << 4;
            const int k = k0 + cb;
            const int cmaj = ((k >> 6) << 9) + g * 64 + (k & 63);
            const u16* src = (const u16*)B + (size_t)(n * 1024 + p0 + r) * 2048 + cmaj;
            *(uint4*)&Bl[r * 40 + cb]     = *(const uint4*)src;
            *(uint4*)&Bl[r * 40 + cb + 8] = *(const uint4*)(src + 8);
        } else if (BMODE == 1) {
            // bf16 i-major: load rows k, k+1; v_perm pair-pack; 8 b32 writes
            const int kp = tid & 15, po = tid >> 4;
            const u16* src = (const u16*)B + (size_t)(ng * 256 + k0 + 2 * kp) * 1024 + p0 + po * 8;
            uint4 r0 = *(const uint4*)src;
            uint4 r1 = *(const uint4*)(src + 1024);
            u32 a0[4] = { r0.x, r0.y, r0.z, r0.w };
            u32 a1[4] = { r1.x, r1.y, r1.z, r1.w };
            #pragma unroll
            for (int j = 0; j < 4; j++) {
                u32 w0 = __builtin_amdgcn_perm(a1[j], a0[j], 0x05040100u);  // p=2j
                u32 w1 = __builtin_amdgcn_perm(a1[j], a0[j], 0x07060302u);  // p=2j+1
                *(u32*)&Bl[(po * 8 + 2 * j    ) * 40 + 2 * kp] = w0;
                *(u32*)&Bl[(po * 8 + 2 * j + 1) * 40 + 2 * kp] = w1;
            }
        } else {
            // f32 i-major (x direct): rows k, k+1; pack2bf(row_k, row_k+1)
            const int kp = tid & 15, po = tid >> 4;
            const float* src = (const float*)B + (size_t)(ng * 256 + k0 + 2 * kp) * 1024 + p0 + po * 8;
            float r0[8], r1[8];
            ld8f(src, r0); ld8f(src + 1024, r1);
            #pragma unroll
            for (int j = 0; j < 8; j++)
                *(u32*)&Bl[(po * 8 + j) * 40 + 2 * kp] = pack2bf(r0[j], r1[j]);
        }
        __syncthreads();
        bf16x8 af[4], bfg[4];
        #pragma unroll
        for (int i = 0; i < 4; i++) af[i]  = *(const bf16x8*)&Al[(mw + i * 16 + lrow) * 40 + lk];
        #pragma unroll
        for (int j = 0; j < 4; j++) bfg[j] = *(const bf16x8*)&Bl[(nw + j * 16 + lrow) * 40 + lk];
        #pragma unroll
        for (int i = 0; i < 4; i++)
            #pragma unroll
            for (int j = 0; j < 4; j++)
                acc[i][j] = __builtin_amdgcn_mfma_f32_16x16x32_bf16(af[i], bfg[j], acc[i][j], 0, 0, 0);
        __syncthreads();
    }

    if (OM == 0) {
        #pragma unroll
        for (int i = 0; i < 4; i++) {
            const int orow = o0 + mw + i * 16 + ((l >> 4) << 2);
            const int cmaj = ((orow >> 6) << 9) + g * 64 + (orow & 63);  // m-major
            #pragma unroll
            for (int j = 0; j < 4; j++) {
                const int p = p0 + nw + j * 16 + lrow;
                float v4[4] = { acc[i][j].x, acc[i][j].y, acc[i][j].z, acc[i][j].w };
                st4bf(out + (size_t)(n * 1024 + p) * 2048 + cmaj, v4);
            }
        }
    } else if (OM == 1) {
        for (int ph = 0; ph < 2; ph++) {
            __syncthreads();
            if (mq == ph) {
                #pragma unroll
                for (int i = 0; i < 4; i++) {
                    const int rl = i * 16 + ((l >> 4) << 2);
                    #pragma unroll
                    for (int j = 0; j < 4; j++) {
                        const int c = nw + j * 16 + lrow;
                        Cl[(rl    ) * 132 + c] = acc[i][j].x;
                        Cl[(rl + 1) * 132 + c] = acc[i][j].y;
                        Cl[(rl + 2) * 132 + c] = acc[i][j].z;
                        Cl[(rl + 3) * 132 + c] = acc[i][j].w;
                    }
                }
            }
            __syncthreads();
            {
                const int row = tid >> 2, pc = (tid & 3) << 5;
                const int og = o0 + ph * 64 + row;
                const float bb = bias ? bias[g * 256 + og] : 0.f;
                u32 pk[16];
                #pragma unroll
                for (int q = 0; q < 8; q++) {
                    float4 f = *(const float4*)&Cl[row * 132 + pc + q * 4];
                    float a0 = f.x + bb, a1 = f.y + bb, a2 = f.z + bb, a3 = f.w + bb;
                    if (RELU) {
                        a0 = fmaxf(a0, 0.f); a1 = fmaxf(a1, 0.f);
                        a2 = fmaxf(a2, 0.f); a3 = fmaxf(a3, 0.f);
                    }
                    pk[q * 2]     = pack2bf(a0, a1);
                    pk[q * 2 + 1] = pack2bf(a2, a3);
                }
                u16* dst = out + (size_t)(ng * 256 + og) * 1024 + p0 + pc;
                #pragma unroll
                for (int q = 0; q < 4; q++) *(uint4*)(dst + q * 8) = *(uint4*)&pk[q * 4];
            }
        }
    } else {
        // ---- fused LN epilogue: per ph, Cl holds one full m-slice (64 d rows) ----
        for (int ph = 0; ph < 2; ph++) {
            const int ms = (ot << 1) | ph;
            __syncthreads();
            if (mq == ph) {
                #pragma unroll
                for (int i = 0; i < 4; i++) {
                    const int rl = i * 16 + ((l >> 4) << 2);
                    #pragma unroll
                    for (int j = 0; j < 4; j++) {
                        const int c = nw + j * 16 + lrow;
                        Cl[(rl    ) * 132 + c] = acc[i][j].x;
                        Cl[(rl + 1) * 132 + c] = acc[i][j].y;
                        Cl[(rl + 2) * 132 + c] = acc[i][j].z;
                        Cl[(rl + 3) * 132 + c] = acc[i][j].w;
                    }
                }
            }
            __syncthreads();
            {   // row pass: += bias + residual (coalesced channel-major read)
                const int row = tid >> 2, pc = (tid & 3) << 5;
                const int o = (ms << 6) + row;
                const float bb = bias[g * 256 + o];
                const size_t rb = (size_t)(ng * 256 + o) * 1024 + p0 + pc;
                float* cp = &Cl[row * 132 + pc];
                #pragma unroll
                for (int c8 = 0; c8 < 4; c8++) {
                    float r8[8];
                    if (RF32) ld8f((const float*)resid + rb + c8 * 8, r8);
                    else      ld8bf((const u16*)resid + rb + c8 * 8, r8);
                    #pragma unroll
                    for (int u = 0; u < 8; u++) cp[c8 * 8 + u] += bb + r8[u];
                }
            }
            __syncthreads();
            {   // column partial stats over the 64 d-rows
                const int c = tid & 127, hh = tid >> 7;
                float sm = 0.f, sq = 0.f;
                #pragma unroll
                for (int r = 0; r < 32; r++) {
                    float v = Cl[(hh * 32 + r) * 132 + c];
                    sm += v; sq += v * v;
                }
                red[hh * 128 + c] = sm; red[256 + hh * 128 + c] = sq;
            }
            __syncthreads();
            if (tid < 128) {
                float s2 = red[tid] + red[128 + tid];
                float q2 = red[256 + tid] + red[384 + tid];
                float mu = s2 * (1.f / 64.f);
                float var = q2 * (1.f / 64.f) - mu * mu;
                mu_s[tid] = mu; rs_s[tid] = rsqrtf(var + 1e-5f);
            }
            __syncthreads();
            {   // normalize + scramble-contiguous write (flat n,p,m,g,d)
                const int c = tid & 127, dh = (tid >> 7) << 5;
                const float mu = mu_s[c], rs = rs_s[c];
                const size_t ob = (size_t)n * 2097152 + (size_t)(p0 + c) * 2048
                                + ms * 512 + g * 64 + dh;
                if (OM == 3) {
                    float* op = (float*)O0 + ob;
                    #pragma unroll
                    for (int q4 = 0; q4 < 8; q4++) {
                        float4 f;
                        f.x = (Cl[(dh + q4 * 4    ) * 132 + c] - mu) * rs * g_s[dh + q4 * 4    ] + b_s[dh + q4 * 4    ];
                        f.y = (Cl[(dh + q4 * 4 + 1) * 132 + c] - mu) * rs * g_s[dh + q4 * 4 + 1] + b_s[dh + q4 * 4 + 1];
                        f.z = (Cl[(dh + q4 * 4 + 2) * 132 + c] - mu) * rs * g_s[dh + q4 * 4 + 2] + b_s[dh + q4 * 4 + 2];
                        f.w = (Cl[(dh + q4 * 4 + 3) * 132 + c] - mu) * rs * g_s[dh + q4 * 4 + 3] + b_s[dh + q4 * 4 + 3];
                        *(float4*)(op + q4 * 4) = f;
                    }
                } else {
                    u16* op = O0 + ob;
                    #pragma unroll
                    for (int q8 = 0; q8 < 4; q8++) {
                        u32 pk[4];
                        #pragma unroll
                        for (int j = 0; j < 4; j++) {
                            const int d = dh + q8 * 8 + j * 2;
                            float a = (Cl[(d    ) * 132 + c] - mu) * rs * g_s[d    ] + b_s[d    ];
                            float b = (Cl[(d + 1) * 132 + c] - mu) * rs * g_s[d + 1] + b_s[d + 1];
                            pk[j] = pack2bf(a, b);
                        }
                        *(uint4*)(op + q8 * 8) = *(uint4*)pk;
                    }
                }
            }
        }
    }
}

// ---------------- attention v9c: 2-phase online softmax, 20.5KB LDS ----------------
// waves_per_eu(4,5): cap the allocator's occupancy target so the ~90 live
// VGPRs fit (budget 512/5 ~ 102) instead of spilling to hit the LDS-derived
// 8-wave target (R18: VGPR pinned 64, 130MB scratch traffic).
#define SBAR() __builtin_amdgcn_sched_barrier(0)
__global__ __launch_bounds__(256)
__attribute__((amdgpu_waves_per_eu(4, 5)))
void attn_kernel(
    const u16* __restrict__ qt, const u16* __restrict__ kt,
    const u16* __restrict__ vt, const u16* __restrict__ relT,
    u16* __restrict__ av) {
    __shared__ __align__(16) char kvb[5 * 4096];
    const int tid = threadIdx.x;
    const int bx = blockIdx.x, n = blockIdx.y;
    const int p = ((bx & 7) << 7) | (bx >> 3);   // XCD-contiguous pixel ranges
    const int ph = p >> 5, pw = p & 31;
    const size_t nimg = (size_t)n * 1024;

    int cpix[9]; unsigned inb = 0;
    #pragma unroll
    for (int ij = 0; ij < 9; ij++) {
        int hs = ph + ij / 3 - 1, wc = pw + ij % 3 - 1;
        if (((unsigned)hs < 32u) && ((unsigned)wc < 32u)) inb |= (1u << ij);
        int hc = hs < 0 ? 0 : (hs > 31 ? 31 : hs);
        int wcl = wc < 0 ? 0 : (wc > 31 ? 31 : wc);
        cpix[ij] = hc * 32 + wcl;                // clamped: OOB loads real (unread) data
    }

    const int e_th = tid & 7, g_th = (tid >> 3) & 7, m_th = tid >> 6;
    const int l = tid & 63;
    const int e_l = l >> 3, d8_l = l & 7;
    const int gsw = e_l * 64 + ((d8_l ^ e_l) & 7) * 8;   // pre-swizzled src (u16, in-slice)
    char* ldst = kvb + m_th * 1024;
    const u16* kb = kt + nimg * 2048 + m_th * 512 + gsw;
    const u16* vb = vt + nimg * 2048 + m_th * 512 + gsw;
    const int qkb = m_th * 1024 + e_th * 128;
    const int db = l & 7, srcb = l & 0x38;
    const int avb = m_th * 1024;

    // ---- [1] q loads (oldest 8 VMEM) ----
    uint4 qv[8];
    {
        const u16* qp = qt + (nimg + p) * 2048 + m_th * 512 + g_th * 64;
        #pragma unroll
        for (int c8 = 0; c8 < 8; c8++) qv[c8] = *(const uint4*)(qp + c8 * 8);
    }
    SBAR();
    // ---- [2] rel gl16 x3 -> S0-2 ----
    #pragma unroll
    for (int idx = 0; idx < 3; idx++)
        gl16(relT + idx * 2048 + m_th * 512 + gsw, ldst + idx * 4096);
    SBAR();
    // ---- [3] K3->S3, K4->S4 ----
    gl16(kb + (size_t)cpix[3] * 2048, ldst + 3 * 4096);
    gl16(kb + (size_t)cpix[4] * 2048, ldst + 4 * 4096);
    SBAR();
    asm volatile("s_waitcnt vmcnt(2)" ::: "memory");    // q + rel landed
    SBAR();
    // ---- [4] qrel on pseudo-tiles S0-2 ----
    float qrel3[3] = {};
    #pragma unroll
    for (int c8 = 0; c8 < 8; c8++) {
        const int sw = ((c8 ^ e_th) & 7) << 4;
        #pragma unroll
        for (int idx = 0; idx < 3; idx++) {
            uint4 rv = *(const uint4*)(kvb + idx * 4096 + qkb + sw);
            qrel3[idx] = dot8bf(qv[c8], rv, qrel3[idx]);
        }
    }
    asm volatile("s_waitcnt lgkmcnt(0)" ::: "memory");
    SBAR();
    // ---- [5] K0-2 -> S0-2 ----
    #pragma unroll
    for (int ij = 0; ij < 3; ij++)
        gl16(kb + (size_t)cpix[ij] * 2048, ldst + ij * 4096);
    SBAR();
    asm volatile("s_waitcnt vmcnt(3)" ::: "memory");    // K3,K4 landed
    SBAR();
    // ---- [6] QK ij3,4 ----
    float sc[5] = {};
    #pragma unroll
    for (int c8 = 0; c8 < 8; c8++) {
        const int sw = ((c8 ^ e_th) & 7) << 4;
        #pragma unroll
        for (int ij = 3; ij < 5; ij++)
            if (inb & (1u << ij)) {
                uint4 kv = *(const uint4*)(kvb + ij * 4096 + qkb + sw);
                sc[ij] = dot8bf(qv[c8], kv, sc[ij]);
            }
    }
    asm volatile("s_waitcnt lgkmcnt(0)" ::: "memory");
    SBAR();
    // ---- [7] V3,V4 -> S3,S4 ----
    gl16(vb + (size_t)cpix[3] * 2048, ldst + 3 * 4096);
    gl16(vb + (size_t)cpix[4] * 2048, ldst + 4 * 4096);
    SBAR();
    asm volatile("s_waitcnt vmcnt(2)" ::: "memory");    // K0-2 landed
    SBAR();
    // ---- [8] QK ij0-2 ----
    #pragma unroll
    for (int c8 = 0; c8 < 8; c8++) {
        const int sw = ((c8 ^ e_th) & 7) << 4;
        #pragma unroll
        for (int ij = 0; ij < 3; ij++)
            if (inb & (1u << ij)) {
                uint4 kv = *(const uint4*)(kvb + ij * 4096 + qkb + sw);
                sc[ij] = dot8bf(qv[c8], kv, sc[ij]);
            }
    }
    asm volatile("s_waitcnt lgkmcnt(0)" ::: "memory");
    SBAR();
    // ---- [9] V0-2 -> S0-2 ----
    #pragma unroll
    for (int ij = 0; ij < 3; ij++)
        gl16(vb + (size_t)cpix[ij] * 2048, ldst + ij * 4096);
    SBAR();
    // ---- [10] softmax A over ij0-4 (V latency hides here) ----
    // OOB entries are qrel-only but participate — matches reference.
    #pragma unroll
    for (int ij = 0; ij < 5; ij++)
        sc[ij] += qrel3[(e_th < 4) ? (ij / 3) : (ij % 3)];
    float mA = sc[0];
    #pragma unroll
    for (int ij = 1; ij < 5; ij++) mA = fmaxf(mA, sc[ij]);
    mA = fmaxf(mA, __shfl_xor(mA, 1));
    mA = fmaxf(mA, __shfl_xor(mA, 2));
    mA = fmaxf(mA, __shfl_xor(mA, 4));
    float sA = 0.f;
    #pragma unroll
    for (int ij = 0; ij < 5; ij++) { sc[ij] = __expf(sc[ij] - mA); sA += sc[ij]; }
    sA += __shfl_xor(sA, 1); sA += __shfl_xor(sA, 2); sA += __shfl_xor(sA, 4);

    asm volatile("s_waitcnt vmcnt(3)" ::: "memory");    // V3,V4 landed
    SBAR();
    // ---- [11] AV ij3,4 (unnormalized expA weights) ----
    float acc[8] = {};
    #pragma unroll
    for (int ij = 3; ij < 5; ij++) {
        if (!(inb & (1u << ij))) continue;
        #pragma unroll
        for (int e = 0; e < 8; e++) {
            const float a = __shfl(sc[ij], srcb | e);
            uint4 vv = *(const uint4*)(kvb + ij * 4096 + avb + e * 128 + (((db ^ e) & 7) << 4));
            float v8[8];
            unpack8(vv, v8);
            #pragma unroll
            for (int u = 0; u < 8; u++) acc[u] += a * v8[u];
        }
    }
    asm volatile("s_waitcnt vmcnt(0)" ::: "memory");    // V0-2 landed
    SBAR();
    // ---- [12] AV ij0-2 ----
    #pragma unroll
    for (int ij = 0; ij < 3; ij++) {
        if (!(inb & (1u << ij))) continue;
        #pragma unroll
        for (int e = 0; e < 8; e++) {
            const float a = __shfl(sc[ij], srcb | e);
            uint4 vv = *(const uint4*)(kvb + ij * 4096 + avb + e * 128 + (((db ^ e) & 7) << 4));
            float v8[8];
            unpack8(vv, v8);
            #pragma unroll
            for (int u = 0; u < 8; u++) acc[u] += a * v8[u];
        }
    }
    asm volatile("s_waitcnt lgkmcnt(0)" ::: "memory");  // all AV-A reads retired
    SBAR();
    // ---- [13] phase B: K5-8 -> S0-3 ----
    #pragma unroll
    for (int t = 0; t < 4; t++)
        gl16(kb + (size_t)cpix[5 + t] * 2048, ldst + t * 4096);
    SBAR();
    asm volatile("s_waitcnt vmcnt(0)" ::: "memory");    // K5-8 landed
    SBAR();
    // ---- [14] QK ij5-8 (slots 0-3) ----
    float scB[4] = {};
    #pragma unroll
    for (int c8 = 0; c8 < 8; c8++) {
        const int sw = ((c8 ^ e_th) & 7) << 4;
        #pragma unroll
        for (int t = 0; t < 4; t++)
            if (inb & (1u << (5 + t))) {
                uint4 kv = *(const uint4*)(kvb + t * 4096 + qkb + sw);
                scB[t] = dot8bf(qv[c8], kv, scB[t]);
            }
    }
    asm volatile("s_waitcnt lgkmcnt(0)" ::: "memory");
    SBAR();
    // ---- [15] V5-8 -> S0-3 ----
    #pragma unroll
    for (int t = 0; t < 4; t++)
        gl16(vb + (size_t)cpix[5 + t] * 2048, ldst + t * 4096);
    SBAR();
    // ---- [16] online merge (V latency hides here) ----
    #pragma unroll
    for (int t = 0; t < 4; t++) {
        const int ij = 5 + t;
        scB[t] += qrel3[(e_th < 4) ? (ij / 3) : (ij % 3)];
    }
    float mB = scB[0];
    #pragma unroll
    for (int t = 1; t < 4; t++) mB = fmaxf(mB, scB[t]);
    mB = fmaxf(mB, __shfl_xor(mB, 1));
    mB = fmaxf(mB, __shfl_xor(mB, 2));
    mB = fmaxf(mB, __shfl_xor(mB, 4));
    const float m = fmaxf(mA, mB);
    const float scaleA = __expf(mA - m);
    #pragma unroll
    for (int u = 0; u < 8; u++) acc[u] *= scaleA;
    sA *= scaleA;
    float sB = 0.f;
    #pragma unroll
    for (int t = 0; t < 4; t++) { scB[t] = __expf(scB[t] - m); sB += scB[t]; }
    sB += __shfl_xor(sB, 1); sB += __shfl_xor(sB, 2); sB += __shfl_xor(sB, 4);
    const float rinv = 1.f / (sA + sB);

    asm volatile("s_waitcnt vmcnt(0)" ::: "memory");    // V5-8 landed
    SBAR();
    // ---- [17] AV ij5-8 (slots 0-3) ----
    __builtin_amdgcn_s_setprio(1);
    #pragma unroll
    for (int t = 0; t < 4; t++) {
        if (!(inb & (1u << (5 + t)))) continue;
        #pragma unroll
        for (int e = 0; e < 8; e++) {
            const float a = __shfl(scB[t], srcb | e);
            uint4 vv = *(const uint4*)(kvb + t * 4096 + avb + e * 128 + (((db ^ e) & 7) << 4));
            float v8[8];
            unpack8(vv, v8);
            #pragma unroll
            for (int u = 0; u < 8; u++) acc[u] += a * v8[u];
        }
    }
    __builtin_amdgcn_s_setprio(0);
    // ---- [18] normalize + store (m-major, 1KB/wave coalesced) ----
    #pragma unroll
    for (int u = 0; u < 8; u++) acc[u] *= rinv;
    const int c0 = m_th * 512 + (l >> 3) * 64 + (l & 7) * 8;
    st4bf(av + (nimg + p) * 2048 + c0, acc);
    st4bf(av + (nimg + p) * 2048 + c0 + 4, acc + 4);
}
#undef SBAR

extern "C" void kernel_launch(void* const* d_in, const int* in_sizes, int n_in,
                              void* d_out, int out_size, void* d_ws, size_t ws_size,
                              hipStream_t stream) {
    const float* x   = (const float*)d_in[0];
    const float* wq  = (const float*)d_in[1];
    const float* wk  = (const float*)d_in[2];
    const float* wv  = (const float*)d_in[3];
    const float* hm  = (const float*)d_in[4];
    const float* wm  = (const float*)d_in[5];
    const float* wc  = (const float*)d_in[6];
    const float* bc  = (const float*)d_in[7];
    const float* wf1 = (const float*)d_in[8];
    const float* bf1 = (const float*)d_in[9];
    const float* wf2 = (const float*)d_in[10];
    const float* bf2w = (const float*)d_in[11];
    const float* g1  = (const float*)d_in[12];
    const float* b1  = (const float*)d_in[13];
    const float* g2  = (const float*)d_in[14];
    const float* b2  = (const float*)d_in[15];
    char* ws = (char*)d_ws;
    u16* bufQ = (u16*)d_out;                     // q -> av (dead before final write)
    u16* relT = bufQ + 8388608;                  // d_out upper half: 12KB rel transpose
    u16* bufK = (u16*)(ws);                      // k -> hidden
    u16* bufV = (u16*)(ws + 16777216);           // v -> t1

    const dim3 gg(8, 2, 32), gq(8, 2, 96), gb(256);
    rel_kernel<<<dim3(1), gb, 0, stream>>>(hm, wm, relT);
    // QKV (x f32 read directly, fused cast; m-major output)
    gemm_kernel<3, 0, 0, 0><<<gq, gb, 0, stream>>>(
        wq, wk, wv, x, nullptr, nullptr, nullptr, nullptr, bufQ, bufK, bufV);
    attn_kernel<<<dim3(1024, 4), gb, 0, stream>>>(bufQ, bufK, bufV, relT, bufQ);
    // wc + LN1 (residual = x f32) -> t1 (bf16, scramble-flat) in bufV
    gemm_kernel<2, 2, 0, 1><<<gg, gb, 0, stream>>>(
        wc, wc, wc, bufQ, bc, x, g1, b1, bufV, bufV, bufV);
    // wf1 + bias + relu -> hidden (channel-major) in bufK
    gemm_kernel<1, 1, 1, 0><<<gg, gb, 0, stream>>>(
        wf1, wf1, wf1, bufV, bf1, nullptr, nullptr, nullptr, bufK, bufK, bufK);
    // wf2 + LN2 (residual = t1 bf16) -> final f32 out
    gemm_kernel<1, 3, 0, 0><<<gg, gb, 0, stream>>>(
        wf2, wf2, wf2, bufK, bf2w, bufV, g2, b2,
        (u16*)d_out, (u16*)d_out, (u16*)d_out);
}

// Round 12
// 320.052 us; speedup vs baseline: 1.2158x; 1.2158x over previous
//
#include <hip/hip_runtime.h>

// ConvMGSA on MI355X. Inputs/outputs FLOAT32; intermediates bf16.
// N=4 G=8 CIN=COUT=256 K=3 M=4 D=64 H=W=32 HW=1024.
//
// R20 = R16 restored (session best, 316.9us). The R17-R19 arc (2-phase
//      online softmax, 20.5KB LDS) is abandoned: the allocator derives its
//      VGPR budget from the LDS-permitted occupancy (20.5KB -> 8 waves/SIMD
//      -> 64 VGPRs) and spills the ~90 live regs; neither launch_bounds
//      arg2 nor amdgpu_waves_per_eu overrides it upward (proven R18/R19).
//      R16's 36.9KB LDS caps occupancy at 4 blocks -> budget 128 -> no
//      spill. attn v8: counted-vmcnt pipeline, rel staged as pseudo-tiles,
//      barrier-free, m-major QKV, clamped OOB loads for static vmcnt counts.
// Buffers: d_out[0:16.8M]=q->av, d_out[+16.8M]=relT; ws[0:16M]=k->hidden;
//          ws[16M:32M]=v->t1.

typedef unsigned short u16;
typedef unsigned int u32;
typedef __attribute__((ext_vector_type(8))) short bf16x8;
typedef __attribute__((ext_vector_type(4))) float f32x4;

__device__ __forceinline__ u32 fbits(float f) { u32 x; __builtin_memcpy(&x, &f, 4); return x; }
__device__ __forceinline__ float bf2f(u32 v) {
    u32 x = v << 16; float f; __builtin_memcpy(&f, &x, 4); return f;
}
__device__ __forceinline__ u16 f2bf(float f) {
    u32 x = fbits(f);
    u32 r = x + 0x7fffu + ((x >> 16) & 1u);
    return (u16)(r >> 16);
}
__device__ __forceinline__ u32 pack2bf(float a, float b) {
    return __builtin_amdgcn_perm(fbits(b) + 0x8000u, fbits(a) + 0x8000u, 0x07060302u);
}

__device__ __forceinline__ void unpack8(uint4 u, float* o) {
    o[0] = bf2f(u.x & 0xffff); o[1] = bf2f(u.x >> 16);
    o[2] = bf2f(u.y & 0xffff); o[3] = bf2f(u.y >> 16);
    o[4] = bf2f(u.z & 0xffff); o[5] = bf2f(u.z >> 16);
    o[6] = bf2f(u.w & 0xffff); o[7] = bf2f(u.w >> 16);
}
__device__ __forceinline__ void ld8bf(const u16* p, float* o) { unpack8(*(const uint4*)p, o); }
__device__ __forceinline__ void ld8f(const float* p, float* o) {
    float4 a = *(const float4*)p, b = *(const float4*)(p + 4);
    o[0] = a.x; o[1] = a.y; o[2] = a.z; o[3] = a.w;
    o[4] = b.x; o[5] = b.y; o[6] = b.z; o[7] = b.w;
}
__device__ __forceinline__ void st4bf(u16* p, const float* v) {
    ushort4 s; s.x = f2bf(v[0]); s.y = f2bf(v[1]); s.z = f2bf(v[2]); s.w = f2bf(v[3]);
    *(ushort4*)p = s;
}

#if defined(__has_builtin)
#if __has_builtin(__builtin_amdgcn_fdot2_f32_bf16)
#define HAVE_BFDOT 1
#endif
#endif
#ifdef HAVE_BFDOT
typedef __attribute__((ext_vector_type(2))) __bf16 v2bf;
__device__ __forceinline__ float dot2bf(u32 a, u32 b, float c) {
    return __builtin_amdgcn_fdot2_f32_bf16(__builtin_bit_cast(v2bf, a),
                                           __builtin_bit_cast(v2bf, b), c, false);
}
#else
__device__ __forceinline__ float dot2bf(u32 a, u32 b, float c) {
    return c + bf2f(a & 0xffff) * bf2f(b & 0xffff) + bf2f(a >> 16) * bf2f(b >> 16);
}
#endif
__device__ __forceinline__ float dot8bf(uint4 a, uint4 b, float c) {
    c = dot2bf(a.x, b.x, c); c = dot2bf(a.y, b.y, c);
    c = dot2bf(a.z, b.z, c); c = dot2bf(a.w, b.w, c);
    return c;
}

typedef const __attribute__((address_space(1))) u32 glob_u32;
typedef __attribute__((address_space(3))) u32 lds_u32;

// async global->LDS, 16B/lane, dest = wave-uniform base + lane*16
__device__ __forceinline__ void gl16(const void* g, void* l) {
    __builtin_amdgcn_global_load_lds((glob_u32*)g, (lds_u32*)l, 16, 0, 0);
}

// ---------------- rel transpose micro-kernel: relT[idx][m][e][d] bf16, 12KB ----------------
__global__ __launch_bounds__(256) void rel_kernel(const float* __restrict__ hm,
                                                  const float* __restrict__ wm,
                                                  u16* __restrict__ relT) {
    const int t = threadIdx.x;
    const int c0 = t << 3;                       // 8 contiguous channels (same e,m)
    const float* rb = (t < 128) ? (hm + (size_t)c0 * 3)
                                : (wm + (size_t)(c0 - 1024) * 3);
    float r[24];
    #pragma unroll
    for (int q = 0; q < 6; q++) {
        float4 f = *(const float4*)(rb + q * 4);
        r[q * 4] = f.x; r[q * 4 + 1] = f.y; r[q * 4 + 2] = f.z; r[q * 4 + 3] = f.w;
    }
    // m-major remap: c = e*256 + m*64 + d  ->  off = m*512 + e*64 + d
    const int obase = ((c0 >> 6) & 3) * 512 + (c0 >> 8) * 64 + (c0 & 63);
    #pragma unroll
    for (int idx = 0; idx < 3; idx++) {
        u32 pk[4];
        #pragma unroll
        for (int j = 0; j < 4; j++)
            pk[j] = pack2bf(r[(2 * j) * 3 + idx], r[(2 * j + 1) * 3 + idx]);
        *(uint4*)(relT + idx * 2048 + obase) = *(uint4*)pk;
    }
}

// ================= MFMA GEMM: C[o][p] = sum_i W[g][o][i] * B[i][p] =================
// BMODE: 1=bf16 i-major, 2=bf16 pixel-major M-MAJOR channels, 3=f32 i-major
// OM: 0=bf16 pixel-major M-MAJOR out (qkv); 1=bf16 channel-major +bias(+relu);
//     2=fused LN, bf16 scramble-flat out; 3=fused LN, f32 scramble-flat out.
// RF32: residual dtype for OM>=2 (1=f32, 0=bf16), channel-major [ng][256][1024].
template<int BMODE, int OM, int RELU, int RF32>
__global__ __launch_bounds__(256) void gemm_kernel(
    const float* __restrict__ A0, const float* __restrict__ A1,
    const float* __restrict__ A2, const void* __restrict__ B,
    const float* __restrict__ bias, const void* __restrict__ resid,
    const float* __restrict__ gamma, const float* __restrict__ beta,
    u16* __restrict__ O0, u16* __restrict__ O1, u16* __restrict__ O2) {
    __shared__ __align__(16) char smem[OM >= 2 ? 37376 : (OM == 1 ? 33792 : 20480)];
    u16* Al = (u16*)smem;              // [128][40] bf16  (o, k)
    u16* Bl = (u16*)(smem + 10240);    // [128][40] bf16  (p, k)
    float* Cl = (float*)smem;          // [64][132] f32   (epilogue transpose)
    float* red  = (float*)(smem + 33792);   // [2][2][128]
    float* mu_s = (float*)(smem + 35840);
    float* rs_s = (float*)(smem + 36352);
    float* g_s  = (float*)(smem + 36864);
    float* b_s  = (float*)(smem + 37120);

    const int tid = threadIdx.x;
    const int pt = blockIdx.x, ot = blockIdx.y;
    const int ngz = blockIdx.z, sel = ngz >> 5, ng = ngz & 31;
    const float* A = (sel == 0) ? A0 : (sel == 1) ? A1 : A2;
    u16* out      = (sel == 0) ? O0 : (sel == 1) ? O1 : O2;
    const int n = ng >> 3, g = ng & 7;
    const int p0 = pt << 7, o0 = ot << 7;
    const float* Ag = A + (size_t)g * 65536;

    if (OM >= 2 && tid < 64) { g_s[tid] = gamma[tid]; b_s[tid] = beta[tid]; }

    const int l = tid & 63, w = tid >> 6;
    const int mq = w >> 1;
    const int mw = mq << 6, nw = (w & 1) << 6;
    const int lrow = l & 15, lk = (l >> 4) << 3;

    f32x4 acc[4][4];
    #pragma unroll
    for (int i = 0; i < 4; i++)
        #pragma unroll
        for (int j = 0; j < 4; j++) acc[i][j] = (f32x4){0.f, 0.f, 0.f, 0.f};

    for (int k0 = 0; k0 < 256; k0 += 32) {
        {   // stage A: f32 weights, rows k-contiguous, pack2bf
            const int r = tid >> 1, cb = (tid & 1) << 4;
            const float* src = Ag + (size_t)(o0 + r) * 256 + k0 + cb;
            u32* dst = (u32*)&Al[r * 40 + cb];
            #pragma unroll
            for (int q = 0; q < 4; q++) {
                float4 f = *(const float4*)(src + q * 4);
                dst[q * 2]     = pack2bf(f.x, f.y);
                dst[q * 2 + 1] = pack2bf(f.z, f.w);
            }
        }
        if (BMODE == 2) {
            // pixel-major, m-major channels: k -> c = (k>>6)*512 + g*64 + (k&63)
            const int r = tid >> 1, cb = (tid & 1) << 4;
            const int k = k0 + cb;
            const int cmaj = ((k >> 6) << 9) + g * 64 + (k & 63);
            const u16* src = (const u16*)B + (size_t)(n * 1024 + p0 + r) * 2048 + cmaj;
            *(uint4*)&Bl[r * 40 + cb]     = *(const uint4*)src;
            *(uint4*)&Bl[r * 40 + cb + 8] = *(const uint4*)(src + 8);
        } else if (BMODE == 1) {
            // bf16 i-major: load rows k, k+1; v_perm pair-pack; 8 b32 writes
            const int kp = tid & 15, po = tid >> 4;
            const u16* src = (const u16*)B + (size_t)(ng * 256 + k0 + 2 * kp) * 1024 + p0 + po * 8;
            uint4 r0 = *(const uint4*)src;
            uint4 r1 = *(const uint4*)(src + 1024);
            u32 a0[4] = { r0.x, r0.y, r0.z, r0.w };
            u32 a1[4] = { r1.x, r1.y, r1.z, r1.w };
            #pragma unroll
            for (int j = 0; j < 4; j++) {
                u32 w0 = __builtin_amdgcn_perm(a1[j], a0[j], 0x05040100u);  // p=2j
                u32 w1 = __builtin_amdgcn_perm(a1[j], a0[j], 0x07060302u);  // p=2j+1
                *(u32*)&Bl[(po * 8 + 2 * j    ) * 40 + 2 * kp] = w0;
                *(u32*)&Bl[(po * 8 + 2 * j + 1) * 40 + 2 * kp] = w1;
            }
        } else {
            // f32 i-major (x direct): rows k, k+1; pack2bf(row_k, row_k+1)
            const int kp = tid & 15, po = tid >> 4;
            const float* src = (const float*)B + (size_t)(ng * 256 + k0 + 2 * kp) * 1024 + p0 + po * 8;
            float r0[8], r1[8];
            ld8f(src, r0); ld8f(src + 1024, r1);
            #pragma unroll
            for (int j = 0; j < 8; j++)
                *(u32*)&Bl[(po * 8 + j) * 40 + 2 * kp] = pack2bf(r0[j], r1[j]);
        }
        __syncthreads();
        bf16x8 af[4], bfg[4];
        #pragma unroll
        for (int i = 0; i < 4; i++) af[i]  = *(const bf16x8*)&Al[(mw + i * 16 + lrow) * 40 + lk];
        #pragma unroll
        for (int j = 0; j < 4; j++) bfg[j] = *(const bf16x8*)&Bl[(nw + j * 16 + lrow) * 40 + lk];
        #pragma unroll
        for (int i = 0; i < 4; i++)
            #pragma unroll
            for (int j = 0; j < 4; j++)
                acc[i][j] = __builtin_amdgcn_mfma_f32_16x16x32_bf16(af[i], bfg[j], acc[i][j], 0, 0, 0);
        __syncthreads();
    }

    if (OM == 0) {
        #pragma unroll
        for (int i = 0; i < 4; i++) {
            const int orow = o0 + mw + i * 16 + ((l >> 4) << 2);
            const int cmaj = ((orow >> 6) << 9) + g * 64 + (orow & 63);  // m-major
            #pragma unroll
            for (int j = 0; j < 4; j++) {
                const int p = p0 + nw + j * 16 + lrow;
                float v4[4] = { acc[i][j].x, acc[i][j].y, acc[i][j].z, acc[i][j].w };
                st4bf(out + (size_t)(n * 1024 + p) * 2048 + cmaj, v4);
            }
        }
    } else if (OM == 1) {
        for (int ph = 0; ph < 2; ph++) {
            __syncthreads();
            if (mq == ph) {
                #pragma unroll
                for (int i = 0; i < 4; i++) {
                    const int rl = i * 16 + ((l >> 4) << 2);
                    #pragma unroll
                    for (int j = 0; j < 4; j++) {
                        const int c = nw + j * 16 + lrow;
                        Cl[(rl    ) * 132 + c] = acc[i][j].x;
                        Cl[(rl + 1) * 132 + c] = acc[i][j].y;
                        Cl[(rl + 2) * 132 + c] = acc[i][j].z;
                        Cl[(rl + 3) * 132 + c] = acc[i][j].w;
                    }
                }
            }
            __syncthreads();
            {
                const int row = tid >> 2, pc = (tid & 3) << 5;
                const int og = o0 + ph * 64 + row;
                const float bb = bias ? bias[g * 256 + og] : 0.f;
                u32 pk[16];
                #pragma unroll
                for (int q = 0; q < 8; q++) {
                    float4 f = *(const float4*)&Cl[row * 132 + pc + q * 4];
                    float a0 = f.x + bb, a1 = f.y + bb, a2 = f.z + bb, a3 = f.w + bb;
                    if (RELU) {
                        a0 = fmaxf(a0, 0.f); a1 = fmaxf(a1, 0.f);
                        a2 = fmaxf(a2, 0.f); a3 = fmaxf(a3, 0.f);
                    }
                    pk[q * 2]     = pack2bf(a0, a1);
                    pk[q * 2 + 1] = pack2bf(a2, a3);
                }
                u16* dst = out + (size_t)(ng * 256 + og) * 1024 + p0 + pc;
                #pragma unroll
                for (int q = 0; q < 4; q++) *(uint4*)(dst + q * 8) = *(uint4*)&pk[q * 4];
            }
        }
    } else {
        // ---- fused LN epilogue: per ph, Cl holds one full m-slice (64 d rows) ----
        for (int ph = 0; ph < 2; ph++) {
            const int ms = (ot << 1) | ph;
            __syncthreads();
            if (mq == ph) {
                #pragma unroll
                for (int i = 0; i < 4; i++) {
                    const int rl = i * 16 + ((l >> 4) << 2);
                    #pragma unroll
                    for (int j = 0; j < 4; j++) {
                        const int c = nw + j * 16 + lrow;
                        Cl[(rl    ) * 132 + c] = acc[i][j].x;
                        Cl[(rl + 1) * 132 + c] = acc[i][j].y;
                        Cl[(rl + 2) * 132 + c] = acc[i][j].z;
                        Cl[(rl + 3) * 132 + c] = acc[i][j].w;
                    }
                }
            }
            __syncthreads();
            {   // row pass: += bias + residual (coalesced channel-major read)
                const int row = tid >> 2, pc = (tid & 3) << 5;
                const int o = (ms << 6) + row;
                const float bb = bias[g * 256 + o];
                const size_t rb = (size_t)(ng * 256 + o) * 1024 + p0 + pc;
                float* cp = &Cl[row * 132 + pc];
                #pragma unroll
                for (int c8 = 0; c8 < 4; c8++) {
                    float r8[8];
                    if (RF32) ld8f((const float*)resid + rb + c8 * 8, r8);
                    else      ld8bf((const u16*)resid + rb + c8 * 8, r8);
                    #pragma unroll
                    for (int u = 0; u < 8; u++) cp[c8 * 8 + u] += bb + r8[u];
                }
            }
            __syncthreads();
            {   // column partial stats over the 64 d-rows
                const int c = tid & 127, hh = tid >> 7;
                float sm = 0.f, sq = 0.f;
                #pragma unroll
                for (int r = 0; r < 32; r++) {
                    float v = Cl[(hh * 32 + r) * 132 + c];
                    sm += v; sq += v * v;
                }
                red[hh * 128 + c] = sm; red[256 + hh * 128 + c] = sq;
            }
            __syncthreads();
            if (tid < 128) {
                float s2 = red[tid] + red[128 + tid];
                float q2 = red[256 + tid] + red[384 + tid];
                float mu = s2 * (1.f / 64.f);
                float var = q2 * (1.f / 64.f) - mu * mu;
                mu_s[tid] = mu; rs_s[tid] = rsqrtf(var + 1e-5f);
            }
            __syncthreads();
            {   // normalize + scramble-contiguous write (flat n,p,m,g,d)
                const int c = tid & 127, dh = (tid >> 7) << 5;
                const float mu = mu_s[c], rs = rs_s[c];
                const size_t ob = (size_t)n * 2097152 + (size_t)(p0 + c) * 2048
                                + ms * 512 + g * 64 + dh;
                if (OM == 3) {
                    float* op = (float*)O0 + ob;
                    #pragma unroll
                    for (int q4 = 0; q4 < 8; q4++) {
                        float4 f;
                        f.x = (Cl[(dh + q4 * 4    ) * 132 + c] - mu) * rs * g_s[dh + q4 * 4    ] + b_s[dh + q4 * 4    ];
                        f.y = (Cl[(dh + q4 * 4 + 1) * 132 + c] - mu) * rs * g_s[dh + q4 * 4 + 1] + b_s[dh + q4 * 4 + 1];
                        f.z = (Cl[(dh + q4 * 4 + 2) * 132 + c] - mu) * rs * g_s[dh + q4 * 4 + 2] + b_s[dh + q4 * 4 + 2];
                        f.w = (Cl[(dh + q4 * 4 + 3) * 132 + c] - mu) * rs * g_s[dh + q4 * 4 + 3] + b_s[dh + q4 * 4 + 3];
                        *(float4*)(op + q4 * 4) = f;
                    }
                } else {
                    u16* op = O0 + ob;
                    #pragma unroll
                    for (int q8 = 0; q8 < 4; q8++) {
                        u32 pk[4];
                        #pragma unroll
                        for (int j = 0; j < 4; j++) {
                            const int d = dh + q8 * 8 + j * 2;
                            float a = (Cl[(d    ) * 132 + c] - mu) * rs * g_s[d    ] + b_s[d    ];
                            float b = (Cl[(d + 1) * 132 + c] - mu) * rs * g_s[d + 1] + b_s[d + 1];
                            pk[j] = pack2bf(a, b);
                        }
                        *(uint4*)(op + q8 * 8) = *(uint4*)pk;
                    }
                }
            }
        }
    }
}

// ---------------- attention v8: counted-vmcnt pipeline, barrier-free ----------------
#define SBAR() __builtin_amdgcn_sched_barrier(0)
__global__ __launch_bounds__(256, 4) void attn_kernel(
    const u16* __restrict__ qt, const u16* __restrict__ kt,
    const u16* __restrict__ vt, const u16* __restrict__ relT,
    u16* __restrict__ av) {
    __shared__ __align__(16) char kvb[9 * 4096];
    const int tid = threadIdx.x;
    const int bx = blockIdx.x, n = blockIdx.y;
    const int p = ((bx & 7) << 7) | (bx >> 3);   // XCD-contiguous pixel ranges
    const int ph = p >> 5, pw = p & 31;
    const size_t nimg = (size_t)n * 1024;

    int cpix[9]; unsigned inb = 0;
    #pragma unroll
    for (int ij = 0; ij < 9; ij++) {
        int hs = ph + ij / 3 - 1, wc = pw + ij % 3 - 1;
        if (((unsigned)hs < 32u) && ((unsigned)wc < 32u)) inb |= (1u << ij);
        int hc = hs < 0 ? 0 : (hs > 31 ? 31 : hs);
        int wcl = wc < 0 ? 0 : (wc > 31 ? 31 : wc);
        cpix[ij] = hc * 32 + wcl;                // clamped: OOB loads real (unread) data
    }

    const int e_th = tid & 7, g_th = (tid >> 3) & 7, m_th = tid >> 6;
    const int l = tid & 63;
    const int e_l = l >> 3, d8_l = l & 7;
    const int gsw = e_l * 64 + ((d8_l ^ e_l) & 7) * 8;   // pre-swizzled src (u16, in-slice)
    char* ldst = kvb + m_th * 1024;
    const u16* kb = kt + nimg * 2048 + m_th * 512 + gsw;
    const u16* vb = vt + nimg * 2048 + m_th * 512 + gsw;

    // ---- [1] q loads (oldest 8 VMEM) ----
    uint4 qv[8];
    {
        const u16* qp = qt + (nimg + p) * 2048 + m_th * 512 + g_th * 64;
        #pragma unroll
        for (int c8 = 0; c8 < 8; c8++) qv[c8] = *(const uint4*)(qp + c8 * 8);
    }
    SBAR();
    // ---- [2] rel gl16 x3 into tiles 0-2 ----
    #pragma unroll
    for (int idx = 0; idx < 3; idx++)
        gl16(relT + idx * 2048 + m_th * 512 + gsw, ldst + idx * 4096);
    SBAR();
    // ---- [3] K gl16 tiles 3-8 ----
    #pragma unroll
    for (int ij = 3; ij < 9; ij++)
        gl16(kb + (size_t)cpix[ij] * 2048, ldst + ij * 4096);
    SBAR();
    asm volatile("s_waitcnt vmcnt(6)" ::: "memory");    // q + rel landed
    SBAR();
    // ---- [4] qrel = QK on pseudo-tiles 0-2 ----
    float qrel3[3] = {};
    const int qkb = m_th * 1024 + e_th * 128;
    #pragma unroll
    for (int c8 = 0; c8 < 8; c8++) {
        const int sw = ((c8 ^ e_th) & 7) << 4;
        #pragma unroll
        for (int idx = 0; idx < 3; idx++) {
            uint4 rv = *(const uint4*)(kvb + idx * 4096 + qkb + sw);
            qrel3[idx] = dot8bf(qv[c8], rv, qrel3[idx]);
        }
    }
    asm volatile("s_waitcnt lgkmcnt(0)" ::: "memory");  // rel reads retired
    SBAR();
    // ---- [5] K gl16 tiles 0-2 (overwrite rel) ----
    #pragma unroll
    for (int ij = 0; ij < 3; ij++)
        gl16(kb + (size_t)cpix[ij] * 2048, ldst + ij * 4096);
    SBAR();
    asm volatile("s_waitcnt vmcnt(3)" ::: "memory");    // K tiles 3-8 landed
    SBAR();
    // ---- [6] QK tiles 3-8 ----
    float sc[9] = {};
    #pragma unroll
    for (int c8 = 0; c8 < 8; c8++) {
        const int sw = ((c8 ^ e_th) & 7) << 4;
        #pragma unroll
        for (int ij = 3; ij < 9; ij++)
            if (inb & (1u << ij)) {
                uint4 kv = *(const uint4*)(kvb + ij * 4096 + qkb + sw);
                sc[ij] = dot8bf(qv[c8], kv, sc[ij]);
            }
    }
    asm volatile("s_waitcnt lgkmcnt(0)" ::: "memory");  // QK(3-8) reads retired
    SBAR();
    // ---- [7] V gl16 tiles 3-8 ----
    #pragma unroll
    for (int ij = 3; ij < 9; ij++)
        gl16(vb + (size_t)cpix[ij] * 2048, ldst + ij * 4096);
    SBAR();
    asm volatile("s_waitcnt vmcnt(6)" ::: "memory");    // K tiles 0-2 landed
    SBAR();
    // ---- [8] QK tiles 0-2 ----
    #pragma unroll
    for (int c8 = 0; c8 < 8; c8++) {
        const int sw = ((c8 ^ e_th) & 7) << 4;
        #pragma unroll
        for (int ij = 0; ij < 3; ij++)
            if (inb & (1u << ij)) {
                uint4 kv = *(const uint4*)(kvb + ij * 4096 + qkb + sw);
                sc[ij] = dot8bf(qv[c8], kv, sc[ij]);
            }
    }
    asm volatile("s_waitcnt lgkmcnt(0)" ::: "memory");  // QK(0-2) reads retired
    SBAR();
    // ---- [9] V gl16 tiles 0-2 ----
    #pragma unroll
    for (int ij = 0; ij < 3; ij++)
        gl16(vb + (size_t)cpix[ij] * 2048, ldst + ij * 4096);
    SBAR();

    // ---- [10] rel add + softmax (V latency hides under this) ----
    // OOB neighbors keep sc=0 but still get the rel term and participate in
    // softmax — matches reference unfold+rel semantics.
    #pragma unroll
    for (int ij = 0; ij < 9; ij++)
        sc[ij] += qrel3[(e_th < 4) ? (ij / 3) : (ij % 3)];

    float mx = sc[0];
    #pragma unroll
    for (int ij = 1; ij < 9; ij++) mx = fmaxf(mx, sc[ij]);
    mx = fmaxf(mx, __shfl_xor(mx, 1));
    mx = fmaxf(mx, __shfl_xor(mx, 2));
    mx = fmaxf(mx, __shfl_xor(mx, 4));
    float sum = 0.f;
    #pragma unroll
    for (int ij = 0; ij < 9; ij++) { sc[ij] = __expf(sc[ij] - mx); sum += sc[ij]; }
    sum += __shfl_xor(sum, 1); sum += __shfl_xor(sum, 2); sum += __shfl_xor(sum, 4);
    const float rinv = 1.f / sum;
    #pragma unroll
    for (int ij = 0; ij < 9; ij++) sc[ij] *= rinv;

    asm volatile("s_waitcnt vmcnt(0)" ::: "memory");    // all V landed
    SBAR();

    // ---- [11] AV: lane (g', db) pulls attn[(m,g'),e,ij] via wave-local shfl ----
    __builtin_amdgcn_s_setprio(1);
    const int db = l & 7, srcb = l & 0x38;
    const int avb = m_th * 1024;
    float acc[8] = {};
    #pragma unroll
    for (int ij = 0; ij < 9; ij++) {
        if (!(inb & (1u << ij))) continue;
        #pragma unroll
        for (int e = 0; e < 8; e++) {
            const float a = __shfl(sc[ij], srcb | e);
            uint4 vv = *(const uint4*)(kvb + ij * 4096 + avb + e * 128 + (((db ^ e) & 7) << 4));
            float v8[8];
            unpack8(vv, v8);
            #pragma unroll
            for (int u = 0; u < 8; u++) acc[u] += a * v8[u];
        }
    }
    __builtin_amdgcn_s_setprio(0);
    // av m-major: c = m*512 + g'*64 + db*8 -> wave writes 1KB contiguous
    const int c0 = m_th * 512 + (l >> 3) * 64 + (l & 7) * 8;
    st4bf(av + (nimg + p) * 2048 + c0, acc);
    st4bf(av + (nimg + p) * 2048 + c0 + 4, acc + 4);
}
#undef SBAR

extern "C" void kernel_launch(void* const* d_in, const int* in_sizes, int n_in,
                              void* d_out, int out_size, void* d_ws, size_t ws_size,
                              hipStream_t stream) {
    const float* x   = (const float*)d_in[0];
    const float* wq  = (const float*)d_in[1];
    const float* wk  = (const float*)d_in[2];
    const float* wv  = (const float*)d_in[3];
    const float* hm  = (const float*)d_in[4];
    const float* wm  = (const float*)d_in[5];
    const float* wc  = (const float*)d_in[6];
    const float* bc  = (const float*)d_in[7];
    const float* wf1 = (const float*)d_in[8];
    const float* bf1 = (const float*)d_in[9];
    const float* wf2 = (const float*)d_in[10];
    const float* bf2w = (const float*)d_in[11];
    const float* g1  = (const float*)d_in[12];
    const float* b1  = (const float*)d_in[13];
    const float* g2  = (const float*)d_in[14];
    const float* b2  = (const float*)d_in[15];
    char* ws = (char*)d_ws;
    u16* bufQ = (u16*)d_out;                     // q -> av (dead before final write)
    u16* relT = bufQ + 8388608;                  // d_out upper half: 12KB rel transpose
    u16* bufK = (u16*)(ws);                      // k -> hidden
    u16* bufV = (u16*)(ws + 16777216);           // v -> t1

    const dim3 gg(8, 2, 32), gq(8, 2, 96), gb(256);
    rel_kernel<<<dim3(1), gb, 0, stream>>>(hm, wm, relT);
    // QKV (x f32 read directly, fused cast; m-major output)
    gemm_kernel<3, 0, 0, 0><<<gq, gb, 0, stream>>>(
        wq, wk, wv, x, nullptr, nullptr, nullptr, nullptr, bufQ, bufK, bufV);
    attn_kernel<<<dim3(1024, 4), gb, 0, stream>>>(bufQ, bufK, bufV, relT, bufQ);
    // wc + LN1 (residual = x f32) -> t1 (bf16, scramble-flat) in bufV
    gemm_kernel<2, 2, 0, 1><<<gg, gb, 0, stream>>>(
        wc, wc, wc, bufQ, bc, x, g1, b1, bufV, bufV, bufV);
    // wf1 + bias + relu -> hidden (channel-major) in bufK
    gemm_kernel<1, 1, 1, 0><<<gg, gb, 0, stream>>>(
        wf1, wf1, wf1, bufV, bf1, nullptr, nullptr, nullptr, bufK, bufK, bufK);
    // wf2 + LN2 (residual = t1 bf16) -> final f32 out
    gemm_kernel<1, 3, 0, 0><<<gg, gb, 0, stream>>>(
        wf2, wf2, wf2, bufK, bf2w, bufV, g2, b2,
        (u16*)d_out, (u16*)d_out, (u16*)d_out);
}

// Round 13
// 303.565 us; speedup vs baseline: 1.2818x; 1.0543x over previous
//
#include <hip/hip_runtime.h>

// ConvMGSA on MI355X. Inputs/outputs FLOAT32; intermediates bf16.
// N=4 G=8 CIN=COUT=256 K=3 M=4 D=64 H=W=32 HW=1024.
//
// R21 = R20 (session-best structure) + weights pre-converted to bf16 once
//      (wcast micro-kernel) so GEMM A-staging is a pure uint4 copy — kills
//      8 pack2bf (~24 VALU ops) per thread per K-step that were re-converting
//      the same f32 weights 8x per block. 5 weights live in d_out's upper
//      half (dead space, after relT); wf2's weights go to ws+32MiB only if
//      ws_size permits (wf2's epilogue overwrites all of d_out), else wf2
//      keeps the f32 A-path. attn v8 unchanged (counted-vmcnt, barrier-free).
// Buffers: d_out[0:16.8M]=q->av, d_out[+16.8M]=relT+wb(5MB); ws[0:16M]=
//          k->hidden; ws[16M:32M]=v->t1; ws[32M:+1M]=wf2 bf16 (if room).

typedef unsigned short u16;
typedef unsigned int u32;
typedef __attribute__((ext_vector_type(8))) short bf16x8;
typedef __attribute__((ext_vector_type(4))) float f32x4;

__device__ __forceinline__ u32 fbits(float f) { u32 x; __builtin_memcpy(&x, &f, 4); return x; }
__device__ __forceinline__ float bf2f(u32 v) {
    u32 x = v << 16; float f; __builtin_memcpy(&f, &x, 4); return f;
}
__device__ __forceinline__ u16 f2bf(float f) {
    u32 x = fbits(f);
    u32 r = x + 0x7fffu + ((x >> 16) & 1u);
    return (u16)(r >> 16);
}
__device__ __forceinline__ u32 pack2bf(float a, float b) {
    return __builtin_amdgcn_perm(fbits(b) + 0x8000u, fbits(a) + 0x8000u, 0x07060302u);
}

__device__ __forceinline__ void unpack8(uint4 u, float* o) {
    o[0] = bf2f(u.x & 0xffff); o[1] = bf2f(u.x >> 16);
    o[2] = bf2f(u.y & 0xffff); o[3] = bf2f(u.y >> 16);
    o[4] = bf2f(u.z & 0xffff); o[5] = bf2f(u.z >> 16);
    o[6] = bf2f(u.w & 0xffff); o[7] = bf2f(u.w >> 16);
}
__device__ __forceinline__ void ld8bf(const u16* p, float* o) { unpack8(*(const uint4*)p, o); }
__device__ __forceinline__ void ld8f(const float* p, float* o) {
    float4 a = *(const float4*)p, b = *(const float4*)(p + 4);
    o[0] = a.x; o[1] = a.y; o[2] = a.z; o[3] = a.w;
    o[4] = b.x; o[5] = b.y; o[6] = b.z; o[7] = b.w;
}
__device__ __forceinline__ void st4bf(u16* p, const float* v) {
    ushort4 s; s.x = f2bf(v[0]); s.y = f2bf(v[1]); s.z = f2bf(v[2]); s.w = f2bf(v[3]);
    *(ushort4*)p = s;
}

#if defined(__has_builtin)
#if __has_builtin(__builtin_amdgcn_fdot2_f32_bf16)
#define HAVE_BFDOT 1
#endif
#endif
#ifdef HAVE_BFDOT
typedef __attribute__((ext_vector_type(2))) __bf16 v2bf;
__device__ __forceinline__ float dot2bf(u32 a, u32 b, float c) {
    return __builtin_amdgcn_fdot2_f32_bf16(__builtin_bit_cast(v2bf, a),
                                           __builtin_bit_cast(v2bf, b), c, false);
}
#else
__device__ __forceinline__ float dot2bf(u32 a, u32 b, float c) {
    return c + bf2f(a & 0xffff) * bf2f(b & 0xffff) + bf2f(a >> 16) * bf2f(b >> 16);
}
#endif
__device__ __forceinline__ float dot8bf(uint4 a, uint4 b, float c) {
    c = dot2bf(a.x, b.x, c); c = dot2bf(a.y, b.y, c);
    c = dot2bf(a.z, b.z, c); c = dot2bf(a.w, b.w, c);
    return c;
}

typedef const __attribute__((address_space(1))) u32 glob_u32;
typedef __attribute__((address_space(3))) u32 lds_u32;

// async global->LDS, 16B/lane, dest = wave-uniform base + lane*16
__device__ __forceinline__ void gl16(const void* g, void* l) {
    __builtin_amdgcn_global_load_lds((glob_u32*)g, (lds_u32*)l, 16, 0, 0);
}

// ---------------- weight f32->bf16 cast: 5 weights -> out5, wf2 -> out1 ----------------
__global__ __launch_bounds__(256) void wcast_kernel(
    const float* __restrict__ w0, const float* __restrict__ w1,
    const float* __restrict__ w2, const float* __restrict__ w3,
    const float* __restrict__ w4, const float* __restrict__ w5,
    u16* __restrict__ out5, u16* __restrict__ out1) {
    const int b = blockIdx.x;
    const int wi = b >> 8, sub = b & 255;
    const size_t off = (size_t)sub * 2048 + threadIdx.x * 8;
    const float* src; u16* dst;
    if (wi < 5) {
        src = (wi == 0) ? w0 : (wi == 1) ? w1 : (wi == 2) ? w2 : (wi == 3) ? w3 : w4;
        dst = out5 + (size_t)wi * 524288;
    } else {
        if (!out1) return;
        src = w5; dst = out1;
    }
    float4 a = *(const float4*)(src + off), c = *(const float4*)(src + off + 4);
    uint4 o;
    o.x = pack2bf(a.x, a.y); o.y = pack2bf(a.z, a.w);
    o.z = pack2bf(c.x, c.y); o.w = pack2bf(c.z, c.w);
    *(uint4*)(dst + off) = o;
}

// ---------------- rel transpose micro-kernel: relT[idx][m][e][d] bf16, 12KB ----------------
__global__ __launch_bounds__(256) void rel_kernel(const float* __restrict__ hm,
                                                  const float* __restrict__ wm,
                                                  u16* __restrict__ relT) {
    const int t = threadIdx.x;
    const int c0 = t << 3;                       // 8 contiguous channels (same e,m)
    const float* rb = (t < 128) ? (hm + (size_t)c0 * 3)
                                : (wm + (size_t)(c0 - 1024) * 3);
    float r[24];
    #pragma unroll
    for (int q = 0; q < 6; q++) {
        float4 f = *(const float4*)(rb + q * 4);
        r[q * 4] = f.x; r[q * 4 + 1] = f.y; r[q * 4 + 2] = f.z; r[q * 4 + 3] = f.w;
    }
    // m-major remap: c = e*256 + m*64 + d  ->  off = m*512 + e*64 + d
    const int obase = ((c0 >> 6) & 3) * 512 + (c0 >> 8) * 64 + (c0 & 63);
    #pragma unroll
    for (int idx = 0; idx < 3; idx++) {
        u32 pk[4];
        #pragma unroll
        for (int j = 0; j < 4; j++)
            pk[j] = pack2bf(r[(2 * j) * 3 + idx], r[(2 * j + 1) * 3 + idx]);
        *(uint4*)(relT + idx * 2048 + obase) = *(uint4*)pk;
    }
}

// ================= MFMA GEMM: C[o][p] = sum_i W[g][o][i] * B[i][p] =================
// BMODE: 1=bf16 i-major, 2=bf16 pixel-major M-MAJOR channels, 3=f32 i-major
// OM: 0=bf16 pixel-major M-MAJOR out (qkv); 1=bf16 channel-major +bias(+relu);
//     2=fused LN, bf16 scramble-flat out; 3=fused LN, f32 scramble-flat out.
// RF32: residual dtype for OM>=2 (1=f32, 0=bf16), channel-major [ng][256][1024].
// AB16: 1 = A is pre-converted bf16 (staging = pure uint4 copy), 0 = f32+pack.
template<int BMODE, int OM, int RELU, int RF32, int AB16>
__global__ __launch_bounds__(256) void gemm_kernel(
    const void* __restrict__ A0, const void* __restrict__ A1,
    const void* __restrict__ A2, const void* __restrict__ B,
    const float* __restrict__ bias, const void* __restrict__ resid,
    const float* __restrict__ gamma, const float* __restrict__ beta,
    u16* __restrict__ O0, u16* __restrict__ O1, u16* __restrict__ O2) {
    __shared__ __align__(16) char smem[OM >= 2 ? 37376 : (OM == 1 ? 33792 : 20480)];
    u16* Al = (u16*)smem;              // [128][40] bf16  (o, k)
    u16* Bl = (u16*)(smem + 10240);    // [128][40] bf16  (p, k)
    float* Cl = (float*)smem;          // [64][132] f32   (epilogue transpose)
    float* red  = (float*)(smem + 33792);   // [2][2][128]
    float* mu_s = (float*)(smem + 35840);
    float* rs_s = (float*)(smem + 36352);
    float* g_s  = (float*)(smem + 36864);
    float* b_s  = (float*)(smem + 37120);

    const int tid = threadIdx.x;
    const int pt = blockIdx.x, ot = blockIdx.y;
    const int ngz = blockIdx.z, sel = ngz >> 5, ng = ngz & 31;
    const void* A = (sel == 0) ? A0 : (sel == 1) ? A1 : A2;
    u16* out      = (sel == 0) ? O0 : (sel == 1) ? O1 : O2;
    const int n = ng >> 3, g = ng & 7;
    const int p0 = pt << 7, o0 = ot << 7;

    if (OM >= 2 && tid < 64) { g_s[tid] = gamma[tid]; b_s[tid] = beta[tid]; }

    const int l = tid & 63, w = tid >> 6;
    const int mq = w >> 1;
    const int mw = mq << 6, nw = (w & 1) << 6;
    const int lrow = l & 15, lk = (l >> 4) << 3;

    f32x4 acc[4][4];
    #pragma unroll
    for (int i = 0; i < 4; i++)
        #pragma unroll
        for (int j = 0; j < 4; j++) acc[i][j] = (f32x4){0.f, 0.f, 0.f, 0.f};

    for (int k0 = 0; k0 < 256; k0 += 32) {
        {   // stage A
            const int r = tid >> 1, cb = (tid & 1) << 4;
            if (AB16) {
                const u16* src = (const u16*)A + (size_t)g * 65536 + (size_t)(o0 + r) * 256 + k0 + cb;
                *(uint4*)&Al[r * 40 + cb]     = *(const uint4*)src;
                *(uint4*)&Al[r * 40 + cb + 8] = *(const uint4*)(src + 8);
            } else {
                const float* src = (const float*)A + (size_t)g * 65536 + (size_t)(o0 + r) * 256 + k0 + cb;
                u32* dst = (u32*)&Al[r * 40 + cb];
                #pragma unroll
                for (int q = 0; q < 4; q++) {
                    float4 f = *(const float4*)(src + q * 4);
                    dst[q * 2]     = pack2bf(f.x, f.y);
                    dst[q * 2 + 1] = pack2bf(f.z, f.w);
                }
            }
        }
        if (BMODE == 2) {
            // pixel-major, m-major channels: k -> c = (k>>6)*512 + g*64 + (k&63)
            const int r = tid >> 1, cb = (tid & 1) << 4;
            const int k = k0 + cb;
            const int cmaj = ((k >> 6) << 9) + g * 64 + (k & 63);
            const u16* src = (const u16*)B + (size_t)(n * 1024 + p0 + r) * 2048 + cmaj;
            *(uint4*)&Bl[r * 40 + cb]     = *(const uint4*)src;
            *(uint4*)&Bl[r * 40 + cb + 8] = *(const uint4*)(src + 8);
        } else if (BMODE == 1) {
            // bf16 i-major: load rows k, k+1; v_perm pair-pack; 8 b32 writes
            const int kp = tid & 15, po = tid >> 4;
            const u16* src = (const u16*)B + (size_t)(ng * 256 + k0 + 2 * kp) * 1024 + p0 + po * 8;
            uint4 r0 = *(const uint4*)src;
            uint4 r1 = *(const uint4*)(src + 1024);
            u32 a0[4] = { r0.x, r0.y, r0.z, r0.w };
            u32 a1[4] = { r1.x, r1.y, r1.z, r1.w };
            #pragma unroll
            for (int j = 0; j < 4; j++) {
                u32 w0 = __builtin_amdgcn_perm(a1[j], a0[j], 0x05040100u);  // p=2j
                u32 w1 = __builtin_amdgcn_perm(a1[j], a0[j], 0x07060302u);  // p=2j+1
                *(u32*)&Bl[(po * 8 + 2 * j    ) * 40 + 2 * kp] = w0;
                *(u32*)&Bl[(po * 8 + 2 * j + 1) * 40 + 2 * kp] = w1;
            }
        } else {
            // f32 i-major (x direct): rows k, k+1; pack2bf(row_k, row_k+1)
            const int kp = tid & 15, po = tid >> 4;
            const float* src = (const float*)B + (size_t)(ng * 256 + k0 + 2 * kp) * 1024 + p0 + po * 8;
            float r0[8], r1[8];
            ld8f(src, r0); ld8f(src + 1024, r1);
            #pragma unroll
            for (int j = 0; j < 8; j++)
                *(u32*)&Bl[(po * 8 + j) * 40 + 2 * kp] = pack2bf(r0[j], r1[j]);
        }
        __syncthreads();
        bf16x8 af[4], bfg[4];
        #pragma unroll
        for (int i = 0; i < 4; i++) af[i]  = *(const bf16x8*)&Al[(mw + i * 16 + lrow) * 40 + lk];
        #pragma unroll
        for (int j = 0; j < 4; j++) bfg[j] = *(const bf16x8*)&Bl[(nw + j * 16 + lrow) * 40 + lk];
        #pragma unroll
        for (int i = 0; i < 4; i++)
            #pragma unroll
            for (int j = 0; j < 4; j++)
                acc[i][j] = __builtin_amdgcn_mfma_f32_16x16x32_bf16(af[i], bfg[j], acc[i][j], 0, 0, 0);
        __syncthreads();
    }

    if (OM == 0) {
        #pragma unroll
        for (int i = 0; i < 4; i++) {
            const int orow = o0 + mw + i * 16 + ((l >> 4) << 2);
            const int cmaj = ((orow >> 6) << 9) + g * 64 + (orow & 63);  // m-major
            #pragma unroll
            for (int j = 0; j < 4; j++) {
                const int p = p0 + nw + j * 16 + lrow;
                float v4[4] = { acc[i][j].x, acc[i][j].y, acc[i][j].z, acc[i][j].w };
                st4bf(out + (size_t)(n * 1024 + p) * 2048 + cmaj, v4);
            }
        }
    } else if (OM == 1) {
        for (int ph = 0; ph < 2; ph++) {
            __syncthreads();
            if (mq == ph) {
                #pragma unroll
                for (int i = 0; i < 4; i++) {
                    const int rl = i * 16 + ((l >> 4) << 2);
                    #pragma unroll
                    for (int j = 0; j < 4; j++) {
                        const int c = nw + j * 16 + lrow;
                        Cl[(rl    ) * 132 + c] = acc[i][j].x;
                        Cl[(rl + 1) * 132 + c] = acc[i][j].y;
                        Cl[(rl + 2) * 132 + c] = acc[i][j].z;
                        Cl[(rl + 3) * 132 + c] = acc[i][j].w;
                    }
                }
            }
            __syncthreads();
            {
                const int row = tid >> 2, pc = (tid & 3) << 5;
                const int og = o0 + ph * 64 + row;
                const float bb = bias ? bias[g * 256 + og] : 0.f;
                u32 pk[16];
                #pragma unroll
                for (int q = 0; q < 8; q++) {
                    float4 f = *(const float4*)&Cl[row * 132 + pc + q * 4];
                    float a0 = f.x + bb, a1 = f.y + bb, a2 = f.z + bb, a3 = f.w + bb;
                    if (RELU) {
                        a0 = fmaxf(a0, 0.f); a1 = fmaxf(a1, 0.f);
                        a2 = fmaxf(a2, 0.f); a3 = fmaxf(a3, 0.f);
                    }
                    pk[q * 2]     = pack2bf(a0, a1);
                    pk[q * 2 + 1] = pack2bf(a2, a3);
                }
                u16* dst = out + (size_t)(ng * 256 + og) * 1024 + p0 + pc;
                #pragma unroll
                for (int q = 0; q < 4; q++) *(uint4*)(dst + q * 8) = *(uint4*)&pk[q * 4];
            }
        }
    } else {
        // ---- fused LN epilogue: per ph, Cl holds one full m-slice (64 d rows) ----
        for (int ph = 0; ph < 2; ph++) {
            const int ms = (ot << 1) | ph;
            __syncthreads();
            if (mq == ph) {
                #pragma unroll
                for (int i = 0; i < 4; i++) {
                    const int rl = i * 16 + ((l >> 4) << 2);
                    #pragma unroll
                    for (int j = 0; j < 4; j++) {
                        const int c = nw + j * 16 + lrow;
                        Cl[(rl    ) * 132 + c] = acc[i][j].x;
                        Cl[(rl + 1) * 132 + c] = acc[i][j].y;
                        Cl[(rl + 2) * 132 + c] = acc[i][j].z;
                        Cl[(rl + 3) * 132 + c] = acc[i][j].w;
                    }
                }
            }
            __syncthreads();
            {   // row pass: += bias + residual (coalesced channel-major read)
                const int row = tid >> 2, pc = (tid & 3) << 5;
                const int o = (ms << 6) + row;
                const float bb = bias[g * 256 + o];
                const size_t rb = (size_t)(ng * 256 + o) * 1024 + p0 + pc;
                float* cp = &Cl[row * 132 + pc];
                #pragma unroll
                for (int c8 = 0; c8 < 4; c8++) {
                    float r8[8];
                    if (RF32) ld8f((const float*)resid + rb + c8 * 8, r8);
                    else      ld8bf((const u16*)resid + rb + c8 * 8, r8);
                    #pragma unroll
                    for (int u = 0; u < 8; u++) cp[c8 * 8 + u] += bb + r8[u];
                }
            }
            __syncthreads();
            {   // column partial stats over the 64 d-rows
                const int c = tid & 127, hh = tid >> 7;
                float sm = 0.f, sq = 0.f;
                #pragma unroll
                for (int r = 0; r < 32; r++) {
                    float v = Cl[(hh * 32 + r) * 132 + c];
                    sm += v; sq += v * v;
                }
                red[hh * 128 + c] = sm; red[256 + hh * 128 + c] = sq;
            }
            __syncthreads();
            if (tid < 128) {
                float s2 = red[tid] + red[128 + tid];
                float q2 = red[256 + tid] + red[384 + tid];
                float mu = s2 * (1.f / 64.f);
                float var = q2 * (1.f / 64.f) - mu * mu;
                mu_s[tid] = mu; rs_s[tid] = rsqrtf(var + 1e-5f);
            }
            __syncthreads();
            {   // normalize + scramble-contiguous write (flat n,p,m,g,d)
                const int c = tid & 127, dh = (tid >> 7) << 5;
                const float mu = mu_s[c], rs = rs_s[c];
                const size_t ob = (size_t)n * 2097152 + (size_t)(p0 + c) * 2048
                                + ms * 512 + g * 64 + dh;
                if (OM == 3) {
                    float* op = (float*)O0 + ob;
                    #pragma unroll
                    for (int q4 = 0; q4 < 8; q4++) {
                        float4 f;
                        f.x = (Cl[(dh + q4 * 4    ) * 132 + c] - mu) * rs * g_s[dh + q4 * 4    ] + b_s[dh + q4 * 4    ];
                        f.y = (Cl[(dh + q4 * 4 + 1) * 132 + c] - mu) * rs * g_s[dh + q4 * 4 + 1] + b_s[dh + q4 * 4 + 1];
                        f.z = (Cl[(dh + q4 * 4 + 2) * 132 + c] - mu) * rs * g_s[dh + q4 * 4 + 2] + b_s[dh + q4 * 4 + 2];
                        f.w = (Cl[(dh + q4 * 4 + 3) * 132 + c] - mu) * rs * g_s[dh + q4 * 4 + 3] + b_s[dh + q4 * 4 + 3];
                        *(float4*)(op + q4 * 4) = f;
                    }
                } else {
                    u16* op = O0 + ob;
                    #pragma unroll
                    for (int q8 = 0; q8 < 4; q8++) {
                        u32 pk[4];
                        #pragma unroll
                        for (int j = 0; j < 4; j++) {
                            const int d = dh + q8 * 8 + j * 2;
                            float a = (Cl[(d    ) * 132 + c] - mu) * rs * g_s[d    ] + b_s[d    ];
                            float b = (Cl[(d + 1) * 132 + c] - mu) * rs * g_s[d + 1] + b_s[d + 1];
                            pk[j] = pack2bf(a, b);
                        }
                        *(uint4*)(op + q8 * 8) = *(uint4*)pk;
                    }
                }
            }
        }
    }
}

// ---------------- attention v8: counted-vmcnt pipeline, barrier-free ----------------
#define SBAR() __builtin_amdgcn_sched_barrier(0)
__global__ __launch_bounds__(256, 4) void attn_kernel(
    const u16* __restrict__ qt, const u16* __restrict__ kt,
    const u16* __restrict__ vt, const u16* __restrict__ relT,
    u16* __restrict__ av) {
    __shared__ __align__(16) char kvb[9 * 4096];
    const int tid = threadIdx.x;
    const int bx = blockIdx.x, n = blockIdx.y;
    const int p = ((bx & 7) << 7) | (bx >> 3);   // XCD-contiguous pixel ranges
    const int ph = p >> 5, pw = p & 31;
    const size_t nimg = (size_t)n * 1024;

    int cpix[9]; unsigned inb = 0;
    #pragma unroll
    for (int ij = 0; ij < 9; ij++) {
        int hs = ph + ij / 3 - 1, wc = pw + ij % 3 - 1;
        if (((unsigned)hs < 32u) && ((unsigned)wc < 32u)) inb |= (1u << ij);
        int hc = hs < 0 ? 0 : (hs > 31 ? 31 : hs);
        int wcl = wc < 0 ? 0 : (wc > 31 ? 31 : wc);
        cpix[ij] = hc * 32 + wcl;                // clamped: OOB loads real (unread) data
    }

    const int e_th = tid & 7, g_th = (tid >> 3) & 7, m_th = tid >> 6;
    const int l = tid & 63;
    const int e_l = l >> 3, d8_l = l & 7;
    const int gsw = e_l * 64 + ((d8_l ^ e_l) & 7) * 8;   // pre-swizzled src (u16, in-slice)
    char* ldst = kvb + m_th * 1024;
    const u16* kb = kt + nimg * 2048 + m_th * 512 + gsw;
    const u16* vb = vt + nimg * 2048 + m_th * 512 + gsw;

    // ---- [1] q loads (oldest 8 VMEM) ----
    uint4 qv[8];
    {
        const u16* qp = qt + (nimg + p) * 2048 + m_th * 512 + g_th * 64;
        #pragma unroll
        for (int c8 = 0; c8 < 8; c8++) qv[c8] = *(const uint4*)(qp + c8 * 8);
    }
    SBAR();
    // ---- [2] rel gl16 x3 into tiles 0-2 ----
    #pragma unroll
    for (int idx = 0; idx < 3; idx++)
        gl16(relT + idx * 2048 + m_th * 512 + gsw, ldst + idx * 4096);
    SBAR();
    // ---- [3] K gl16 tiles 3-8 ----
    #pragma unroll
    for (int ij = 3; ij < 9; ij++)
        gl16(kb + (size_t)cpix[ij] * 2048, ldst + ij * 4096);
    SBAR();
    asm volatile("s_waitcnt vmcnt(6)" ::: "memory");    // q + rel landed
    SBAR();
    // ---- [4] qrel = QK on pseudo-tiles 0-2 ----
    float qrel3[3] = {};
    const int qkb = m_th * 1024 + e_th * 128;
    #pragma unroll
    for (int c8 = 0; c8 < 8; c8++) {
        const int sw = ((c8 ^ e_th) & 7) << 4;
        #pragma unroll
        for (int idx = 0; idx < 3; idx++) {
            uint4 rv = *(const uint4*)(kvb + idx * 4096 + qkb + sw);
            qrel3[idx] = dot8bf(qv[c8], rv, qrel3[idx]);
        }
    }
    asm volatile("s_waitcnt lgkmcnt(0)" ::: "memory");  // rel reads retired
    SBAR();
    // ---- [5] K gl16 tiles 0-2 (overwrite rel) ----
    #pragma unroll
    for (int ij = 0; ij < 3; ij++)
        gl16(kb + (size_t)cpix[ij] * 2048, ldst + ij * 4096);
    SBAR();
    asm volatile("s_waitcnt vmcnt(3)" ::: "memory");    // K tiles 3-8 landed
    SBAR();
    // ---- [6] QK tiles 3-8 ----
    float sc[9] = {};
    #pragma unroll
    for (int c8 = 0; c8 < 8; c8++) {
        const int sw = ((c8 ^ e_th) & 7) << 4;
        #pragma unroll
        for (int ij = 3; ij < 9; ij++)
            if (inb & (1u << ij)) {
                uint4 kv = *(const uint4*)(kvb + ij * 4096 + qkb + sw);
                sc[ij] = dot8bf(qv[c8], kv, sc[ij]);
            }
    }
    asm volatile("s_waitcnt lgkmcnt(0)" ::: "memory");  // QK(3-8) reads retired
    SBAR();
    // ---- [7] V gl16 tiles 3-8 ----
    #pragma unroll
    for (int ij = 3; ij < 9; ij++)
        gl16(vb + (size_t)cpix[ij] * 2048, ldst + ij * 4096);
    SBAR();
    asm volatile("s_waitcnt vmcnt(6)" ::: "memory");    // K tiles 0-2 landed
    SBAR();
    // ---- [8] QK tiles 0-2 ----
    #pragma unroll
    for (int c8 = 0; c8 < 8; c8++) {
        const int sw = ((c8 ^ e_th) & 7) << 4;
        #pragma unroll
        for (int ij = 0; ij < 3; ij++)
            if (inb & (1u << ij)) {
                uint4 kv = *(const uint4*)(kvb + ij * 4096 + qkb + sw);
                sc[ij] = dot8bf(qv[c8], kv, sc[ij]);
            }
    }
    asm volatile("s_waitcnt lgkmcnt(0)" ::: "memory");  // QK(0-2) reads retired
    SBAR();
    // ---- [9] V gl16 tiles 0-2 ----
    #pragma unroll
    for (int ij = 0; ij < 3; ij++)
        gl16(vb + (size_t)cpix[ij] * 2048, ldst + ij * 4096);
    SBAR();

    // ---- [10] rel add + softmax (V latency hides under this) ----
    // OOB neighbors keep sc=0 but still get the rel term and participate in
    // softmax — matches reference unfold+rel semantics.
    #pragma unroll
    for (int ij = 0; ij < 9; ij++)
        sc[ij] += qrel3[(e_th < 4) ? (ij / 3) : (ij % 3)];

    float mx = sc[0];
    #pragma unroll
    for (int ij = 1; ij < 9; ij++) mx = fmaxf(mx, sc[ij]);
    mx = fmaxf(mx, __shfl_xor(mx, 1));
    mx = fmaxf(mx, __shfl_xor(mx, 2));
    mx = fmaxf(mx, __shfl_xor(mx, 4));
    float sum = 0.f;
    #pragma unroll
    for (int ij = 0; ij < 9; ij++) { sc[ij] = __expf(sc[ij] - mx); sum += sc[ij]; }
    sum += __shfl_xor(sum, 1); sum += __shfl_xor(sum, 2); sum += __shfl_xor(sum, 4);
    const float rinv = 1.f / sum;
    #pragma unroll
    for (int ij = 0; ij < 9; ij++) sc[ij] *= rinv;

    asm volatile("s_waitcnt vmcnt(0)" ::: "memory");    // all V landed
    SBAR();

    // ---- [11] AV: lane (g', db) pulls attn[(m,g'),e,ij] via wave-local shfl ----
    __builtin_amdgcn_s_setprio(1);
    const int db = l & 7, srcb = l & 0x38;
    const int avb = m_th * 1024;
    float acc[8] = {};
    #pragma unroll
    for (int ij = 0; ij < 9; ij++) {
        if (!(inb & (1u << ij))) continue;
        #pragma unroll
        for (int e = 0; e < 8; e++) {
            const float a = __shfl(sc[ij], srcb | e);
            uint4 vv = *(const uint4*)(kvb + ij * 4096 + avb + e * 128 + (((db ^ e) & 7) << 4));
            float v8[8];
            unpack8(vv, v8);
            #pragma unroll
            for (int u = 0; u < 8; u++) acc[u] += a * v8[u];
        }
    }
    __builtin_amdgcn_s_setprio(0);
    // av m-major: c = m*512 + g'*64 + db*8 -> wave writes 1KB contiguous
    const int c0 = m_th * 512 + (l >> 3) * 64 + (l & 7) * 8;
    st4bf(av + (nimg + p) * 2048 + c0, acc);
    st4bf(av + (nimg + p) * 2048 + c0 + 4, acc + 4);
}
#undef SBAR

extern "C" void kernel_launch(void* const* d_in, const int* in_sizes, int n_in,
                              void* d_out, int out_size, void* d_ws, size_t ws_size,
                              hipStream_t stream) {
    const float* x   = (const float*)d_in[0];
    const float* wq  = (const float*)d_in[1];
    const float* wk  = (const float*)d_in[2];
    const float* wv  = (const float*)d_in[3];
    const float* hm  = (const float*)d_in[4];
    const float* wm  = (const float*)d_in[5];
    const float* wc  = (const float*)d_in[6];
    const float* bc  = (const float*)d_in[7];
    const float* wf1 = (const float*)d_in[8];
    const float* bf1 = (const float*)d_in[9];
    const float* wf2 = (const float*)d_in[10];
    const float* bf2w = (const float*)d_in[11];
    const float* g1  = (const float*)d_in[12];
    const float* b1  = (const float*)d_in[13];
    const float* g2  = (const float*)d_in[14];
    const float* b2  = (const float*)d_in[15];
    char* ws = (char*)d_ws;
    u16* bufQ = (u16*)d_out;                     // q -> av (dead before final write)
    u16* relT = bufQ + 8388608;                  // d_out upper half: 12KB rel transpose
    u16* wb   = bufQ + 8388608 + 32768;          // d_out upper half: 5MB bf16 weights
    u16* bufK = (u16*)(ws);                      // k -> hidden
    u16* bufV = (u16*)(ws + 16777216);           // v -> t1
    // wf2 weights: d_out is fully overwritten by the final dispatch, so wf2's
    // bf16 copy must live in ws past the 32MiB we already use — if there's room.
    const bool extraWs = ws_size >= (33554432ull + 1048576ull);
    u16* wb2 = extraWs ? (u16*)(ws + 33554432) : nullptr;

    const dim3 gg(8, 2, 32), gq(8, 2, 96), gb(256);
    wcast_kernel<<<dim3(1536), gb, 0, stream>>>(wq, wk, wv, wc, wf1, wf2, wb, wb2);
    rel_kernel<<<dim3(1), gb, 0, stream>>>(hm, wm, relT);
    // QKV (x f32 read directly, fused cast; bf16 A; m-major output)
    gemm_kernel<3, 0, 0, 0, 1><<<gq, gb, 0, stream>>>(
        wb, wb + 524288, wb + 1048576, x, nullptr, nullptr, nullptr, nullptr,
        bufQ, bufK, bufV);
    attn_kernel<<<dim3(1024, 4), gb, 0, stream>>>(bufQ, bufK, bufV, relT, bufQ);
    // wc + LN1 (residual = x f32) -> t1 (bf16, scramble-flat) in bufV
    gemm_kernel<2, 2, 0, 1, 1><<<gg, gb, 0, stream>>>(
        wb + 1572864, wb + 1572864, wb + 1572864, bufQ, bc, x, g1, b1,
        bufV, bufV, bufV);
    // wf1 + bias + relu -> hidden (channel-major) in bufK
    gemm_kernel<1, 1, 1, 0, 1><<<gg, gb, 0, stream>>>(
        wb + 2097152, wb + 2097152, wb + 2097152, bufV, bf1, nullptr, nullptr, nullptr,
        bufK, bufK, bufK);
    // wf2 + LN2 (residual = t1 bf16) -> final f32 out
    if (extraWs) {
        gemm_kernel<1, 3, 0, 0, 1><<<gg, gb, 0, stream>>>(
            wb2, wb2, wb2, bufK, bf2w, bufV, g2, b2,
            (u16*)d_out, (u16*)d_out, (u16*)d_out);
    } else {
        gemm_kernel<1, 3, 0, 0, 0><<<gg, gb, 0, stream>>>(
            wf2, wf2, wf2, bufK, bf2w, bufV, g2, b2,
            (u16*)d_out, (u16*)d_out, (u16*)d_out);
    }
}